// Round 1
// baseline (927.258 us; speedup 1.0000x reference)
//
#include <hip/hip_runtime.h>

#define N_NODES 100000
#define N_EDGES 20000
#define N_INC   800000
#define TDIM    384
#define HID     128

// ---------------- projection: H = A @ W + b  (fp32 vector tiling) -------------
// BM=64, BN=128, BK=32; 256 threads; each thread 4 rows x 8 cols (two float4 col groups)
__global__ __launch_bounds__(256) void proj_kernel(
    const float* __restrict__ A, const float* __restrict__ W,
    const float* __restrict__ bias, float* __restrict__ H)
{
  __shared__ float As[64][36];   // [row][k], +4 pad keeps 16B align & breaks bank stride
  __shared__ float Bs[32][128];  // [k][col]
  const int tid = threadIdx.x;
  const int tx = tid & 15;
  const int ty = tid >> 4;
  const int bm0 = blockIdx.x * 64;

  float acc[4][8];
#pragma unroll
  for (int i = 0; i < 4; i++)
#pragma unroll
    for (int j = 0; j < 8; j++) acc[i][j] = 0.f;

  for (int k0 = 0; k0 < TDIM; k0 += 32) {
    {
      int r = tid >> 3;
      int kk = (tid & 7) * 4;
#pragma unroll
      for (int i = 0; i < 2; ++i) {
        int row = r + i * 32;
        int grow = bm0 + row;
        if (grow >= N_NODES) grow = N_NODES - 1;  // clamp; stores are guarded
        const float4 v = *(const float4*)(A + (size_t)grow * TDIM + k0 + kk);
        *(float4*)(&As[row][kk]) = v;
      }
    }
    {
#pragma unroll
      for (int l = 0; l < 4; ++l) {
        int fidx = tid + l * 256;          // 0..1023 float4 slots
        int kr = fidx >> 5;                // 0..31
        int c4 = (fidx & 31) * 4;          // 0..124
        const float4 v = *(const float4*)(W + (size_t)(k0 + kr) * HID + c4);
        *(float4*)(&Bs[kr][c4]) = v;
      }
    }
    __syncthreads();
#pragma unroll
    for (int k = 0; k < 32; ++k) {
      float a[4];
#pragma unroll
      for (int i = 0; i < 4; i++) a[i] = As[ty * 4 + i][k];
      float4 b0 = *(const float4*)(&Bs[k][tx * 4]);
      float4 b1 = *(const float4*)(&Bs[k][64 + tx * 4]);
      float b[8] = {b0.x, b0.y, b0.z, b0.w, b1.x, b1.y, b1.z, b1.w};
#pragma unroll
      for (int i = 0; i < 4; i++)
#pragma unroll
        for (int j = 0; j < 8; j++) acc[i][j] += a[i] * b[j];
    }
    __syncthreads();
  }
  float4 bv0 = *(const float4*)(bias + tx * 4);
  float4 bv1 = *(const float4*)(bias + 64 + tx * 4);
#pragma unroll
  for (int i = 0; i < 4; i++) {
    int row = bm0 + ty * 4 + i;
    if (row < N_NODES) {
      float4 o0 = {acc[i][0] + bv0.x, acc[i][1] + bv0.y, acc[i][2] + bv0.z, acc[i][3] + bv0.w};
      float4 o1 = {acc[i][4] + bv1.x, acc[i][5] + bv1.y, acc[i][6] + bv1.z, acc[i][7] + bv1.w};
      *(float4*)(H + (size_t)row * HID + tx * 4) = o0;
      *(float4*)(H + (size_t)row * HID + 64 + tx * 4) = o1;
    }
  }
}

// ---------------- CSR build ----------------
__global__ void count_kernel(const int* __restrict__ node_idx, const int* __restrict__ edge_idx,
                             int* __restrict__ ecnt, int* __restrict__ ncnt)
{
  int i = blockIdx.x * blockDim.x + threadIdx.x;
  if (i >= N_INC) return;
  atomicAdd(&ecnt[edge_idx[i]], 1);
  atomicAdd(&ncnt[node_idx[i]], 1);
}

__global__ __launch_bounds__(1024) void scan_block(const int* __restrict__ cnt, int* __restrict__ ptr,
                                                   int* __restrict__ partials, int n)
{
  __shared__ int s[1024];
  int tid = threadIdx.x;
  int i = blockIdx.x * 1024 + tid;
  int v = (i < n) ? cnt[i] : 0;
  s[tid] = v;
  __syncthreads();
  for (int off = 1; off < 1024; off <<= 1) {
    int add = (tid >= off) ? s[tid - off] : 0;
    __syncthreads();
    s[tid] += add;
    __syncthreads();
  }
  if (i < n) ptr[i] = s[tid] - v;            // exclusive
  if (tid == 1023) partials[blockIdx.x] = s[1023];
}

__global__ __launch_bounds__(1024) void scan_partials(int* __restrict__ partials, int nb,
                                                      int* __restrict__ ptr, int n)
{
  __shared__ int s[1024];
  int tid = threadIdx.x;
  int v = (tid < nb) ? partials[tid] : 0;
  s[tid] = v;
  __syncthreads();
  for (int off = 1; off < 1024; off <<= 1) {
    int add = (tid >= off) ? s[tid - off] : 0;
    __syncthreads();
    s[tid] += add;
    __syncthreads();
  }
  if (tid < nb) partials[tid] = s[tid] - v;  // exclusive block offsets
  if (tid == 0) ptr[n] = s[1023];            // grand total
}

__global__ void scan_add(int* __restrict__ ptr, const int* __restrict__ partials, int n)
{
  int i = blockIdx.x * 1024 + threadIdx.x;
  if (i < n) ptr[i] += partials[blockIdx.x];
}

__global__ void fill_kernel(const int* __restrict__ node_idx, const int* __restrict__ edge_idx,
                            const int* __restrict__ eptr, int* __restrict__ ecur, int* __restrict__ ecols,
                            const int* __restrict__ nptr, int* __restrict__ ncur, int* __restrict__ ncols)
{
  int i = blockIdx.x * blockDim.x + threadIdx.x;
  if (i >= N_INC) return;
  int nd = node_idx[i], ed = edge_idx[i];
  int p = atomicAdd(&ecur[ed], 1);
  ecols[eptr[ed] + p] = nd;
  int q = atomicAdd(&ncur[nd], 1);
  ncols[nptr[nd] + q] = ed;
}

// ---------------- column sum over H (for g = mean) ----------------
__global__ __launch_bounds__(128) void colsum_kernel(const float* __restrict__ H, float* __restrict__ gsum)
{
  int c = threadIdx.x;
  float acc = 0.f;
  for (int r = blockIdx.x; r < N_NODES; r += gridDim.x)
    acc += H[(size_t)r * HID + c];
  atomicAdd(&gsum[c], acc);
}

// ---------------- hypernet: scale = relu(g@W1+b1)@W2 + b2 ----------------
__global__ __launch_bounds__(128) void scale_kernel(const float* __restrict__ gsum,
    const float* __restrict__ W1, const float* __restrict__ b1,
    const float* __restrict__ W2, const float* __restrict__ b2,
    float* __restrict__ scale)
{
  __shared__ float g[HID], t[HID];
  int c = threadIdx.x;
  g[c] = gsum[c] * (1.0f / (float)N_NODES);
  __syncthreads();
  float acc = b1[c];
#pragma unroll 8
  for (int k = 0; k < HID; ++k) acc += g[k] * W1[(size_t)k * HID + c];
  t[c] = fmaxf(acc, 0.f);
  __syncthreads();
  float acc2 = b2[c];
#pragma unroll 8
  for (int k = 0; k < HID; ++k) acc2 += t[k] * W2[(size_t)k * HID + c];
  scale[c] = acc2;
}

// ---------------- edge aggregation: e_feat[e] = mean_{nodes in e} h[node] ----------------
__global__ __launch_bounds__(256) void edge_agg_kernel(
    const float* __restrict__ H, const int* __restrict__ eptr,
    const int* __restrict__ ecols, float* __restrict__ E)
{
  int gw = (blockIdx.x * blockDim.x + threadIdx.x) >> 6;
  int lane = threadIdx.x & 63;
  if (gw >= N_EDGES) return;
  int p0 = eptr[gw], p1 = eptr[gw + 1];
  float2 acc = make_float2(0.f, 0.f);
  for (int base = p0; base < p1; base += 64) {
    int cnt = min(64, p1 - base);
    int idx = (base + lane < p1) ? ecols[base + lane] : 0;
    for (int j = 0; j < cnt; ++j) {
      int nd = __shfl(idx, j, 64);
      float2 v = *(const float2*)(H + (size_t)nd * HID + lane * 2);
      acc.x += v.x;
      acc.y += v.y;
    }
  }
  float inv = 1.f / (float)max(p1 - p0, 1);
  float2 o = make_float2(acc.x * inv, acc.y * inv);
  *(float2*)(E + (size_t)gw * HID + lane * 2) = o;
}

// ---------------- node aggregation + scale + relu (writes h in place) ----------------
__global__ __launch_bounds__(256) void node_agg_kernel(
    const float* __restrict__ E, const int* __restrict__ nptr,
    const int* __restrict__ ncols, const float* __restrict__ scale,
    float* __restrict__ H)
{
  int gw = (blockIdx.x * blockDim.x + threadIdx.x) >> 6;
  int lane = threadIdx.x & 63;
  if (gw >= N_NODES) return;
  int p0 = nptr[gw], p1 = nptr[gw + 1];
  float2 acc = make_float2(0.f, 0.f);
  for (int base = p0; base < p1; base += 64) {
    int cnt = min(64, p1 - base);
    int idx = (base + lane < p1) ? ncols[base + lane] : 0;
    for (int j = 0; j < cnt; ++j) {
      int ed = __shfl(idx, j, 64);
      float2 v = *(const float2*)(E + (size_t)ed * HID + lane * 2);
      acc.x += v.x;
      acc.y += v.y;
    }
  }
  float inv = 1.f / (float)max(p1 - p0, 1);
  float2 sc = *(const float2*)(scale + lane * 2);
  float2 o;
  o.x = fmaxf(acc.x * inv * sc.x, 0.f);
  o.y = fmaxf(acc.y * inv * sc.y, 0.f);
  *(float2*)(H + (size_t)gw * HID + lane * 2) = o;
}

// ---------------- launch ----------------
extern "C" void kernel_launch(void* const* d_in, const int* in_sizes, int n_in,
                              void* d_out, int out_size, void* d_ws, size_t ws_size,
                              hipStream_t stream)
{
  const float* text = (const float*)d_in[0];
  const float* Wp   = (const float*)d_in[1];
  const float* bp   = (const float*)d_in[2];
  const float* W1a  = (const float*)d_in[3];
  const float* b1a  = (const float*)d_in[4];
  const float* W2a  = (const float*)d_in[5];
  const float* b2a  = (const float*)d_in[6];
  const float* W1b  = (const float*)d_in[7];
  const float* b1b  = (const float*)d_in[8];
  const float* W2b  = (const float*)d_in[9];
  const float* b2b  = (const float*)d_in[10];
  const int* node_idx = (const int*)d_in[11];
  const int* edge_idx = (const int*)d_in[12];
  float* H = (float*)d_out;

  // ---- workspace layout (bytes) ----
  char* ws = (char*)d_ws;
  // zeroed region first: ecnt, ncnt, ecur, ncur, gsum0, gsum1
  int*   ecnt  = (int*)(ws + 0);                         // 20000
  int*   ncnt  = (int*)(ws + 80000);                     // 100000
  int*   ecur  = (int*)(ws + 480000);                    // 20000
  int*   ncur  = (int*)(ws + 560000);                    // 100000
  float* gsum0 = (float*)(ws + 960000);                  // 128
  float* gsum1 = (float*)(ws + 960512);                  // 128
  const size_t zero_bytes = 961024;
  int*   eptr  = (int*)(ws + 961024);                    // 20001
  int*   nptr  = (int*)(ws + 1041152);                   // 100001
  int*   ecols = (int*)(ws + 1441280);                   // 800000
  int*   ncols = (int*)(ws + 4641280);                   // 800000
  float* scale0 = (float*)(ws + 7841280);                // 128
  float* scale1 = (float*)(ws + 7841792);                // 128
  int*   partials = (int*)(ws + 7842304);                // 1024
  float* efeat = (float*)(ws + 7846400);                 // 20000*128 -> end ~18.1 MB

  hipMemsetAsync(ws, 0, zero_bytes, stream);

  // projection
  proj_kernel<<<(N_NODES + 63) / 64, 256, 0, stream>>>(text, Wp, bp, H);

  // CSR build
  count_kernel<<<N_INC / 256, 256, 0, stream>>>(node_idx, edge_idx, ecnt, ncnt);
  scan_block<<<(N_EDGES + 1023) / 1024, 1024, 0, stream>>>(ecnt, eptr, partials, N_EDGES);
  scan_partials<<<1, 1024, 0, stream>>>(partials, (N_EDGES + 1023) / 1024, eptr, N_EDGES);
  scan_add<<<(N_EDGES + 1023) / 1024, 1024, 0, stream>>>(eptr, partials, N_EDGES);
  scan_block<<<(N_NODES + 1023) / 1024, 1024, 0, stream>>>(ncnt, nptr, partials, N_NODES);
  scan_partials<<<1, 1024, 0, stream>>>(partials, (N_NODES + 1023) / 1024, nptr, N_NODES);
  scan_add<<<(N_NODES + 1023) / 1024, 1024, 0, stream>>>(nptr, partials, N_NODES);
  fill_kernel<<<N_INC / 256, 256, 0, stream>>>(node_idx, edge_idx, eptr, ecur, ecols, nptr, ncur, ncols);

  // layer 1
  colsum_kernel<<<2048, 128, 0, stream>>>(H, gsum0);
  scale_kernel<<<1, 128, 0, stream>>>(gsum0, W1a, b1a, W2a, b2a, scale0);
  edge_agg_kernel<<<(N_EDGES * 64) / 256, 256, 0, stream>>>(H, eptr, ecols, efeat);
  node_agg_kernel<<<(N_NODES * 64) / 256, 256, 0, stream>>>(efeat, nptr, ncols, scale0, H);

  // layer 2
  colsum_kernel<<<2048, 128, 0, stream>>>(H, gsum1);
  scale_kernel<<<1, 128, 0, stream>>>(gsum1, W1b, b1b, W2b, b2b, scale1);
  edge_agg_kernel<<<(N_EDGES * 64) / 256, 256, 0, stream>>>(H, eptr, ecols, efeat);
  node_agg_kernel<<<(N_NODES * 64) / 256, 256, 0, stream>>>(efeat, nptr, ncols, scale1, H);
}

// Round 2
// 889.217 us; speedup vs baseline: 1.0428x; 1.0428x over previous
//
#include <hip/hip_runtime.h>

#define N_NODES 100000
#define N_EDGES 20000
#define N_INC   800000
#define TDIM    384
#define HID     128

typedef __attribute__((ext_vector_type(8))) short short8;
typedef __attribute__((ext_vector_type(4))) float floatx4;

static __device__ __forceinline__ unsigned short f32_bf16_rne(float f) {
  unsigned int u = __float_as_uint(f);
  unsigned int r = u + 0x7FFFu + ((u >> 16) & 1u);
  return (unsigned short)(r >> 16);
}

// ---------------- W prep: split W into hi/lo bf16 in B-fragment order ---------
// frag layout for mfma_f32_16x16x32_bf16 B: n = lane&15, k = (lane>>4)*8 + j
// storage: Bh[((kk*8 + nt)*64 + lane)*8 + j]
__global__ __launch_bounds__(64) void wprep_kernel(
    const float* __restrict__ W, unsigned short* __restrict__ Bh,
    unsigned short* __restrict__ Bl)
{
  int b = blockIdx.x;              // 0..95 = kk*8 + nt
  int lane = threadIdx.x;
  int kk = b >> 3, nt = b & 7;
  int col = lane & 15, quad = lane >> 4;
  size_t o = ((size_t)b * 64 + lane) * 8;
#pragma unroll
  for (int j = 0; j < 8; ++j) {
    int k = kk * 32 + quad * 8 + j;
    float w = W[(size_t)k * HID + nt * 16 + col];
    unsigned short h = f32_bf16_rne(w);
    float hf = __uint_as_float((unsigned int)h << 16);
    Bh[o + j] = h;
    Bl[o + j] = f32_bf16_rne(w - hf);
  }
}

// ---------------- projection via MFMA bf16x3: H = A @ W + b ------------------
// block = 256 (4 waves); wave tile = 32 rows x 128 cols (2 mtiles x 8 ntiles)
__global__ __launch_bounds__(256) void proj_mfma(
    const float* __restrict__ A, const unsigned short* __restrict__ Bh,
    const unsigned short* __restrict__ Bl, const float* __restrict__ bias,
    float* __restrict__ H)
{
  const int tid = threadIdx.x;
  const int wave = tid >> 6;
  const int lane = tid & 63;
  const int col = lane & 15;
  const int quad = lane >> 4;
  const int m0 = blockIdx.x * 128 + wave * 32;

  floatx4 acc[2][8];
#pragma unroll
  for (int mt = 0; mt < 2; ++mt)
#pragma unroll
    for (int nt = 0; nt < 8; ++nt) acc[mt][nt] = (floatx4){0.f, 0.f, 0.f, 0.f};

  const float* arow[2];
#pragma unroll
  for (int mt = 0; mt < 2; ++mt) {
    int r = m0 + mt * 16 + col;
    if (r >= N_NODES) r = N_NODES - 1;   // clamp loads; stores guarded
    arow[mt] = A + (size_t)r * TDIM + quad * 8;
  }

  float ra[2][8];
#pragma unroll
  for (int mt = 0; mt < 2; ++mt) {
    *(float4*)(&ra[mt][0]) = *(const float4*)(arow[mt]);
    *(float4*)(&ra[mt][4]) = *(const float4*)(arow[mt] + 4);
  }

  for (int kk = 0; kk < 12; ++kk) {
    float rn[2][8];
    if (kk < 11) {
#pragma unroll
      for (int mt = 0; mt < 2; ++mt) {
        *(float4*)(&rn[mt][0]) = *(const float4*)(arow[mt] + (kk + 1) * 32);
        *(float4*)(&rn[mt][4]) = *(const float4*)(arow[mt] + (kk + 1) * 32 + 4);
      }
    }
    // B fragments (hi/lo), coalesced 16B/lane, L2-hot
    short8 bh[8], bl[8];
#pragma unroll
    for (int nt = 0; nt < 8; ++nt) {
      size_t o = ((size_t)(kk * 8 + nt) * 64 + lane) * 8;
      bh[nt] = *(const short8*)(Bh + o);
      bl[nt] = *(const short8*)(Bl + o);
    }
    // split A into hi/lo bf16 fragments
    short8 ah[2], al[2];
#pragma unroll
    for (int mt = 0; mt < 2; ++mt) {
#pragma unroll
      for (int j = 0; j < 8; ++j) {
        float f = ra[mt][j];
        unsigned short h = f32_bf16_rne(f);
        float hf = __uint_as_float((unsigned int)h << 16);
        ah[mt][j] = (short)h;
        al[mt][j] = (short)f32_bf16_rne(f - hf);
      }
    }
#pragma unroll
    for (int nt = 0; nt < 8; ++nt) {
#pragma unroll
      for (int mt = 0; mt < 2; ++mt) {
        acc[mt][nt] = __builtin_amdgcn_mfma_f32_16x16x32_bf16(ah[mt], bh[nt], acc[mt][nt], 0, 0, 0);
        acc[mt][nt] = __builtin_amdgcn_mfma_f32_16x16x32_bf16(al[mt], bh[nt], acc[mt][nt], 0, 0, 0);
        acc[mt][nt] = __builtin_amdgcn_mfma_f32_16x16x32_bf16(ah[mt], bl[nt], acc[mt][nt], 0, 0, 0);
      }
    }
#pragma unroll
    for (int mt = 0; mt < 2; ++mt)
#pragma unroll
      for (int j = 0; j < 8; ++j) ra[mt][j] = rn[mt][j];
  }

  // epilogue: + bias, store (C/D: col=lane&15, row=quad*4+reg)
#pragma unroll
  for (int nt = 0; nt < 8; ++nt) {
    float bv = bias[nt * 16 + col];
#pragma unroll
    for (int mt = 0; mt < 2; ++mt) {
#pragma unroll
      for (int r = 0; r < 4; ++r) {
        int row = m0 + mt * 16 + quad * 4 + r;
        if (row < N_NODES)
          H[(size_t)row * HID + nt * 16 + col] = acc[mt][nt][r] + bv;
      }
    }
  }
}

// ---------------- CSR build ----------------
__global__ void count_kernel(const int* __restrict__ node_idx, const int* __restrict__ edge_idx,
                             int* __restrict__ ecnt, int* __restrict__ ncnt)
{
  int i = blockIdx.x * blockDim.x + threadIdx.x;
  if (i >= N_INC) return;
  atomicAdd(&ecnt[edge_idx[i]], 1);
  atomicAdd(&ncnt[node_idx[i]], 1);
}

__global__ __launch_bounds__(1024) void scan_block(const int* __restrict__ cnt, int* __restrict__ ptr,
                                                   int* __restrict__ partials, int n)
{
  __shared__ int s[1024];
  int tid = threadIdx.x;
  int i = blockIdx.x * 1024 + tid;
  int v = (i < n) ? cnt[i] : 0;
  s[tid] = v;
  __syncthreads();
  for (int off = 1; off < 1024; off <<= 1) {
    int add = (tid >= off) ? s[tid - off] : 0;
    __syncthreads();
    s[tid] += add;
    __syncthreads();
  }
  if (i < n) ptr[i] = s[tid] - v;            // exclusive
  if (tid == 1023) partials[blockIdx.x] = s[1023];
}

__global__ __launch_bounds__(1024) void scan_partials(int* __restrict__ partials, int nb,
                                                      int* __restrict__ ptr, int n)
{
  __shared__ int s[1024];
  int tid = threadIdx.x;
  int v = (tid < nb) ? partials[tid] : 0;
  s[tid] = v;
  __syncthreads();
  for (int off = 1; off < 1024; off <<= 1) {
    int add = (tid >= off) ? s[tid - off] : 0;
    __syncthreads();
    s[tid] += add;
    __syncthreads();
  }
  if (tid < nb) partials[tid] = s[tid] - v;  // exclusive block offsets
  if (tid == 0) ptr[n] = s[1023];            // grand total
}

__global__ void scan_add(int* __restrict__ ptr, const int* __restrict__ partials, int n)
{
  int i = blockIdx.x * 1024 + threadIdx.x;
  if (i < n) ptr[i] += partials[blockIdx.x];
}

__global__ void fill_kernel(const int* __restrict__ node_idx, const int* __restrict__ edge_idx,
                            const int* __restrict__ eptr, int* __restrict__ ecur, int* __restrict__ ecols,
                            const int* __restrict__ nptr, int* __restrict__ ncur, int* __restrict__ ncols)
{
  int i = blockIdx.x * blockDim.x + threadIdx.x;
  if (i >= N_INC) return;
  int nd = node_idx[i], ed = edge_idx[i];
  int p = atomicAdd(&ecur[ed], 1);
  ecols[eptr[ed] + p] = nd;
  int q = atomicAdd(&ncur[nd], 1);
  ncols[nptr[nd] + q] = ed;
}

// ---------------- column sum over H (for g = mean) ----------------
__global__ __launch_bounds__(128) void colsum_kernel(const float* __restrict__ H, float* __restrict__ gsum)
{
  int c = threadIdx.x;
  float acc = 0.f;
  for (int r = blockIdx.x; r < N_NODES; r += gridDim.x)
    acc += H[(size_t)r * HID + c];
  atomicAdd(&gsum[c], acc);
}

// ---------------- hypernet: scale = relu(g@W1+b1)@W2 + b2 ----------------
__global__ __launch_bounds__(128) void scale_kernel(const float* __restrict__ gsum,
    const float* __restrict__ W1, const float* __restrict__ b1,
    const float* __restrict__ W2, const float* __restrict__ b2,
    float* __restrict__ scale)
{
  __shared__ float g[HID], t[HID];
  int c = threadIdx.x;
  g[c] = gsum[c] * (1.0f / (float)N_NODES);
  __syncthreads();
  float acc = b1[c];
#pragma unroll 8
  for (int k = 0; k < HID; ++k) acc += g[k] * W1[(size_t)k * HID + c];
  t[c] = fmaxf(acc, 0.f);
  __syncthreads();
  float acc2 = b2[c];
#pragma unroll 8
  for (int k = 0; k < HID; ++k) acc2 += t[k] * W2[(size_t)k * HID + c];
  scale[c] = acc2;
}

// ---------------- edge aggregation: e_feat[e] = mean_{nodes in e} h[node] ----
__global__ __launch_bounds__(256) void edge_agg_kernel(
    const float* __restrict__ H, const int* __restrict__ eptr,
    const int* __restrict__ ecols, float* __restrict__ E)
{
  int gw = (blockIdx.x * blockDim.x + threadIdx.x) >> 6;
  int lane = threadIdx.x & 63;
  if (gw >= N_EDGES) return;
  int p0 = eptr[gw], p1 = eptr[gw + 1];
  float2 acc = make_float2(0.f, 0.f);
  for (int base = p0; base < p1; base += 64) {
    int cnt = min(64, p1 - base);
    int idx = (base + lane < p1) ? ecols[base + lane] : 0;
    for (int j = 0; j < cnt; ++j) {
      int nd = __shfl(idx, j, 64);
      float2 v = *(const float2*)(H + (size_t)nd * HID + lane * 2);
      acc.x += v.x;
      acc.y += v.y;
    }
  }
  float inv = 1.f / (float)max(p1 - p0, 1);
  float2 o = make_float2(acc.x * inv, acc.y * inv);
  *(float2*)(E + (size_t)gw * HID + lane * 2) = o;
}

// ---------------- node aggregation + scale + relu (writes h in place) --------
__global__ __launch_bounds__(256) void node_agg_kernel(
    const float* __restrict__ E, const int* __restrict__ nptr,
    const int* __restrict__ ncols, const float* __restrict__ scale,
    float* __restrict__ H)
{
  int gw = (blockIdx.x * blockDim.x + threadIdx.x) >> 6;
  int lane = threadIdx.x & 63;
  if (gw >= N_NODES) return;
  int p0 = nptr[gw], p1 = nptr[gw + 1];
  float2 acc = make_float2(0.f, 0.f);
  for (int base = p0; base < p1; base += 64) {
    int cnt = min(64, p1 - base);
    int idx = (base + lane < p1) ? ncols[base + lane] : 0;
    for (int j = 0; j < cnt; ++j) {
      int ed = __shfl(idx, j, 64);
      float2 v = *(const float2*)(E + (size_t)ed * HID + lane * 2);
      acc.x += v.x;
      acc.y += v.y;
    }
  }
  float inv = 1.f / (float)max(p1 - p0, 1);
  float2 sc = *(const float2*)(scale + lane * 2);
  float2 o;
  o.x = fmaxf(acc.x * inv * sc.x, 0.f);
  o.y = fmaxf(acc.y * inv * sc.y, 0.f);
  *(float2*)(H + (size_t)gw * HID + lane * 2) = o;
}

// ---------------- launch ----------------
extern "C" void kernel_launch(void* const* d_in, const int* in_sizes, int n_in,
                              void* d_out, int out_size, void* d_ws, size_t ws_size,
                              hipStream_t stream)
{
  const float* text = (const float*)d_in[0];
  const float* Wp   = (const float*)d_in[1];
  const float* bp   = (const float*)d_in[2];
  const float* W1a  = (const float*)d_in[3];
  const float* b1a  = (const float*)d_in[4];
  const float* W2a  = (const float*)d_in[5];
  const float* b2a  = (const float*)d_in[6];
  const float* W1b  = (const float*)d_in[7];
  const float* b1b  = (const float*)d_in[8];
  const float* W2b  = (const float*)d_in[9];
  const float* b2b  = (const float*)d_in[10];
  const int* node_idx = (const int*)d_in[11];
  const int* edge_idx = (const int*)d_in[12];
  float* H = (float*)d_out;

  // ---- workspace layout (bytes) ----
  char* ws = (char*)d_ws;
  int*   ecnt  = (int*)(ws + 0);                         // 20000
  int*   ncnt  = (int*)(ws + 80000);                     // 100000
  int*   ecur  = (int*)(ws + 480000);                    // 20000
  int*   ncur  = (int*)(ws + 560000);                    // 100000
  float* gsum0 = (float*)(ws + 960000);                  // 128
  float* gsum1 = (float*)(ws + 960512);                  // 128
  const size_t zero_bytes = 961024;
  int*   eptr  = (int*)(ws + 961024);                    // 20001
  int*   nptr  = (int*)(ws + 1041152);                   // 100001
  int*   ecols = (int*)(ws + 1441280);                   // 800000 ints
  int*   ncols = (int*)(ws + 4641280);                   // 800000 ints
  float* scale0 = (float*)(ws + 7841280);                // 128
  float* scale1 = (float*)(ws + 7841792);                // 128
  int*   partials = (int*)(ws + 7842304);                // 1024
  float* efeat = (float*)(ws + 7846400);                 // 20000*128 floats
  // Bh/Bl overlay the ecols region: only live from wprep until fill_kernel
  unsigned short* Bh = (unsigned short*)(ws + 1441280);  // 49152 shorts (96KB)
  unsigned short* Bl = (unsigned short*)(ws + 1539584);  // 49152 shorts

  hipMemsetAsync(ws, 0, zero_bytes, stream);

  // projection (MFMA bf16x3)
  wprep_kernel<<<96, 64, 0, stream>>>(Wp, Bh, Bl);
  proj_mfma<<<(N_NODES + 127) / 128, 256, 0, stream>>>(text, Bh, Bl, bp, H);

  // CSR build
  count_kernel<<<N_INC / 256, 256, 0, stream>>>(node_idx, edge_idx, ecnt, ncnt);
  scan_block<<<(N_EDGES + 1023) / 1024, 1024, 0, stream>>>(ecnt, eptr, partials, N_EDGES);
  scan_partials<<<1, 1024, 0, stream>>>(partials, (N_EDGES + 1023) / 1024, eptr, N_EDGES);
  scan_add<<<(N_EDGES + 1023) / 1024, 1024, 0, stream>>>(eptr, partials, N_EDGES);
  scan_block<<<(N_NODES + 1023) / 1024, 1024, 0, stream>>>(ncnt, nptr, partials, N_NODES);
  scan_partials<<<1, 1024, 0, stream>>>(partials, (N_NODES + 1023) / 1024, nptr, N_NODES);
  scan_add<<<(N_NODES + 1023) / 1024, 1024, 0, stream>>>(nptr, partials, N_NODES);
  fill_kernel<<<N_INC / 256, 256, 0, stream>>>(node_idx, edge_idx, eptr, ecur, ecols, nptr, ncur, ncols);

  // layer 1
  colsum_kernel<<<2048, 128, 0, stream>>>(H, gsum0);
  scale_kernel<<<1, 128, 0, stream>>>(gsum0, W1a, b1a, W2a, b2a, scale0);
  edge_agg_kernel<<<(N_EDGES * 64) / 256, 256, 0, stream>>>(H, eptr, ecols, efeat);
  node_agg_kernel<<<(N_NODES * 64) / 256, 256, 0, stream>>>(efeat, nptr, ncols, scale0, H);

  // layer 2
  colsum_kernel<<<2048, 128, 0, stream>>>(H, gsum1);
  scale_kernel<<<1, 128, 0, stream>>>(gsum1, W1b, b1b, W2b, b2b, scale1);
  edge_agg_kernel<<<(N_EDGES * 64) / 256, 256, 0, stream>>>(H, eptr, ecols, efeat);
  node_agg_kernel<<<(N_NODES * 64) / 256, 256, 0, stream>>>(efeat, nptr, ncols, scale1, H);
}

// Round 3
// 761.994 us; speedup vs baseline: 1.2169x; 1.1670x over previous
//
#include <hip/hip_runtime.h>

#define N_NODES 100000
#define N_EDGES 20000
#define N_INC   800000
#define TDIM    384
#define HID     128
#define NOFF    800000   // node-ptr offset in merged scan

typedef __attribute__((ext_vector_type(8))) short short8;
typedef __attribute__((ext_vector_type(4))) float floatx4;

static __device__ __forceinline__ unsigned short f32_bf16_rne(float f) {
  unsigned int u = __float_as_uint(f);
  unsigned int r = u + 0x7FFFu + ((u >> 16) & 1u);
  return (unsigned short)(r >> 16);
}

// ---------------- W prep: split W into hi/lo bf16 in B-fragment order ---------
// frag layout for mfma_f32_16x16x32_bf16 B: n = lane&15, k = (lane>>4)*8 + j
// storage: Bh[(kk*512 + nt*64 + lane)*8 + j]  (contiguous 8KB per kk-tile)
__global__ __launch_bounds__(64) void wprep_kernel(
    const float* __restrict__ W, unsigned short* __restrict__ Bh,
    unsigned short* __restrict__ Bl)
{
  int b = blockIdx.x;              // 0..95 = kk*8 + nt
  int lane = threadIdx.x;
  int kk = b >> 3, nt = b & 7;
  int col = lane & 15, quad = lane >> 4;
  size_t o = ((size_t)b * 64 + lane) * 8;
#pragma unroll
  for (int j = 0; j < 8; ++j) {
    int k = kk * 32 + quad * 8 + j;
    float w = W[(size_t)k * HID + nt * 16 + col];
    unsigned short h = f32_bf16_rne(w);
    float hf = __uint_as_float((unsigned int)h << 16);
    Bh[o + j] = h;
    Bl[o + j] = f32_bf16_rne(w - hf);
  }
}

// ---------------- projection via MFMA bf16x3: H = A @ W + b ------------------
// block = 256 (4 waves); block tile 64 rows; wave tile = 16 rows x 128 cols.
// B tile for each kk staged once into LDS, shared by all 4 waves.
__global__ __launch_bounds__(256) void proj_mfma(
    const float* __restrict__ A, const unsigned short* __restrict__ Bh,
    const unsigned short* __restrict__ Bl, const float* __restrict__ bias,
    float* __restrict__ H)
{
  __shared__ unsigned short BhS[512 * 8];   // 8 KB: [nt*64+lane][8]
  __shared__ unsigned short BlS[512 * 8];   // 8 KB
  const int tid = threadIdx.x;
  const int wave = tid >> 6;
  const int lane = tid & 63;
  const int col = lane & 15;
  const int quad = lane >> 4;
  const int m0 = blockIdx.x * 64 + wave * 16;

  floatx4 acc[8];
#pragma unroll
  for (int nt = 0; nt < 8; ++nt) acc[nt] = (floatx4){0.f, 0.f, 0.f, 0.f};

  int r = m0 + col;
  if (r >= N_NODES) r = N_NODES - 1;        // clamp loads; stores guarded
  const float* arow = A + (size_t)r * TDIM + quad * 8;

  float ra[8];
  *(float4*)(&ra[0]) = *(const float4*)(arow);
  *(float4*)(&ra[4]) = *(const float4*)(arow + 4);

  for (int kk = 0; kk < 12; ++kk) {
    // stage B tile kk (contiguous 8KB each): thread t copies chunks t and t+256
    short8 sh0 = *(const short8*)(Bh + ((size_t)kk * 512 + tid) * 8);
    short8 sh1 = *(const short8*)(Bh + ((size_t)kk * 512 + tid + 256) * 8);
    short8 sl0 = *(const short8*)(Bl + ((size_t)kk * 512 + tid) * 8);
    short8 sl1 = *(const short8*)(Bl + ((size_t)kk * 512 + tid + 256) * 8);
    __syncthreads();   // previous iteration's LDS reads complete before overwrite
    *(short8*)(BhS + (size_t)tid * 8) = sh0;
    *(short8*)(BhS + ((size_t)tid + 256) * 8) = sh1;
    *(short8*)(BlS + (size_t)tid * 8) = sl0;
    *(short8*)(BlS + ((size_t)tid + 256) * 8) = sl1;

    // prefetch next A chunk
    float rn[8];
    if (kk < 11) {
      *(float4*)(&rn[0]) = *(const float4*)(arow + (kk + 1) * 32);
      *(float4*)(&rn[4]) = *(const float4*)(arow + (kk + 1) * 32 + 4);
    }

    // split A into hi/lo bf16 fragments
    short8 ah, al;
#pragma unroll
    for (int j = 0; j < 8; ++j) {
      float f = ra[j];
      unsigned short h = f32_bf16_rne(f);
      float hf = __uint_as_float((unsigned int)h << 16);
      ah[j] = (short)h;
      al[j] = (short)f32_bf16_rne(f - hf);
    }
    __syncthreads();   // staging visible to all waves

#pragma unroll
    for (int nt = 0; nt < 8; ++nt) {
      short8 bh = *(const short8*)(BhS + ((size_t)nt * 64 + lane) * 8);
      short8 bl = *(const short8*)(BlS + ((size_t)nt * 64 + lane) * 8);
      acc[nt] = __builtin_amdgcn_mfma_f32_16x16x32_bf16(ah, bh, acc[nt], 0, 0, 0);
      acc[nt] = __builtin_amdgcn_mfma_f32_16x16x32_bf16(al, bh, acc[nt], 0, 0, 0);
      acc[nt] = __builtin_amdgcn_mfma_f32_16x16x32_bf16(ah, bl, acc[nt], 0, 0, 0);
    }
#pragma unroll
    for (int j = 0; j < 8; ++j) ra[j] = rn[j];
  }

  // epilogue: + bias, store (C/D: col=lane&15, row=quad*4+reg)
#pragma unroll
  for (int nt = 0; nt < 8; ++nt) {
    float bv = bias[nt * 16 + col];
#pragma unroll
    for (int rr = 0; rr < 4; ++rr) {
      int row = m0 + quad * 4 + rr;
      if (row < N_NODES)
        H[(size_t)row * HID + nt * 16 + col] = acc[nt][rr] + bv;
    }
  }
}

// ---------------- CSR build ----------------
__global__ void count_kernel(const int* __restrict__ node_idx, const int* __restrict__ edge_idx,
                             int* __restrict__ ecnt, int* __restrict__ ncnt)
{
  int i = blockIdx.x * blockDim.x + threadIdx.x;
  if (i >= N_INC) return;
  atomicAdd(&ecnt[edge_idx[i]], 1);
  atomicAdd(&ncnt[node_idx[i]], 1);
}

__global__ __launch_bounds__(1024) void scan_block(const int* __restrict__ cnt, int* __restrict__ ptr,
                                                   int* __restrict__ partials, int n)
{
  __shared__ int s[1024];
  int tid = threadIdx.x;
  int i = blockIdx.x * 1024 + tid;
  int v = (i < n) ? cnt[i] : 0;
  s[tid] = v;
  __syncthreads();
  for (int off = 1; off < 1024; off <<= 1) {
    int add = (tid >= off) ? s[tid - off] : 0;
    __syncthreads();
    s[tid] += add;
    __syncthreads();
  }
  if (i < n) ptr[i] = s[tid] - v;            // exclusive
  if (tid == 1023) partials[blockIdx.x] = s[1023];
}

__global__ __launch_bounds__(1024) void scan_partials(int* __restrict__ partials, int nb,
                                                      int* __restrict__ ptr, int n)
{
  __shared__ int s[1024];
  int tid = threadIdx.x;
  int v = (tid < nb) ? partials[tid] : 0;
  s[tid] = v;
  __syncthreads();
  for (int off = 1; off < 1024; off <<= 1) {
    int add = (tid >= off) ? s[tid - off] : 0;
    __syncthreads();
    s[tid] += add;
    __syncthreads();
  }
  if (tid < nb) partials[tid] = s[tid] - v;  // exclusive block offsets
  if (tid == 0) ptr[n] = s[1023];            // grand total
}

__global__ void scan_add(int* __restrict__ ptr, const int* __restrict__ partials, int n)
{
  int i = blockIdx.x * 1024 + threadIdx.x;
  if (i < n) ptr[i] += partials[blockIdx.x];
}

__global__ void fill_kernel(const int* __restrict__ node_idx, const int* __restrict__ edge_idx,
                            const int* __restrict__ eptr, int* __restrict__ ecur, int* __restrict__ ecols,
                            const int* __restrict__ nptr, int* __restrict__ ncur, int* __restrict__ ncols)
{
  int i = blockIdx.x * blockDim.x + threadIdx.x;
  if (i >= N_INC) return;
  int nd = node_idx[i], ed = edge_idx[i];
  int p = atomicAdd(&ecur[ed], 1);
  ecols[eptr[ed] + p] = nd;
  int q = atomicAdd(&ncur[nd], 1);
  ncols[(nptr[nd] - NOFF) + q] = ed;
}

// ---------------- column sum over H (for g = mean) ----------------
// 256 blocks x 4 waves; per-wave register partials -> LDS reduce -> 1 atomic/col/block
__global__ __launch_bounds__(256) void colsum_kernel(const float* __restrict__ H, float* __restrict__ gsum)
{
  __shared__ float red[4][HID];
  int wave = threadIdx.x >> 6, lane = threadIdx.x & 63;
  float sx = 0.f, sy = 0.f;
  for (int r = blockIdx.x * 4 + wave; r < N_NODES; r += gridDim.x * 4) {
    float2 v = *(const float2*)(H + (size_t)r * HID + lane * 2);
    sx += v.x;
    sy += v.y;
  }
  red[wave][lane * 2] = sx;
  red[wave][lane * 2 + 1] = sy;
  __syncthreads();
  if (wave == 0) {
    float ax = red[0][lane * 2] + red[1][lane * 2] + red[2][lane * 2] + red[3][lane * 2];
    float ay = red[0][lane * 2 + 1] + red[1][lane * 2 + 1] + red[2][lane * 2 + 1] + red[3][lane * 2 + 1];
    atomicAdd(&gsum[lane * 2], ax);
    atomicAdd(&gsum[lane * 2 + 1], ay);
  }
}

// ---------------- hypernet: scale = relu(g@W1+b1)@W2 + b2 ----------------
__global__ __launch_bounds__(128) void scale_kernel(const float* __restrict__ gsum,
    const float* __restrict__ W1, const float* __restrict__ b1,
    const float* __restrict__ W2, const float* __restrict__ b2,
    float* __restrict__ scale)
{
  __shared__ float g[HID], t[HID];
  int c = threadIdx.x;
  g[c] = gsum[c] * (1.0f / (float)N_NODES);
  __syncthreads();
  float acc = b1[c];
#pragma unroll 8
  for (int k = 0; k < HID; ++k) acc += g[k] * W1[(size_t)k * HID + c];
  t[c] = fmaxf(acc, 0.f);
  __syncthreads();
  float acc2 = b2[c];
#pragma unroll 8
  for (int k = 0; k < HID; ++k) acc2 += t[k] * W2[(size_t)k * HID + c];
  scale[c] = acc2;
}

// ---------------- edge aggregation: e_feat[e] = mean_{nodes in e} h[node] ----
__global__ __launch_bounds__(256) void edge_agg_kernel(
    const float* __restrict__ H, const int* __restrict__ eptr,
    const int* __restrict__ ecols, float* __restrict__ E)
{
  int gw = (blockIdx.x * blockDim.x + threadIdx.x) >> 6;
  int lane = threadIdx.x & 63;
  if (gw >= N_EDGES) return;
  int p0 = eptr[gw], p1 = eptr[gw + 1];
  float2 a0 = make_float2(0.f, 0.f), a1 = make_float2(0.f, 0.f);
  for (int base = p0; base < p1; base += 64) {
    int cnt = min(64, p1 - base);
    int idx = (base + lane < p1) ? ecols[base + lane] : 0;
    int j = 0;
    for (; j + 1 < cnt; j += 2) {
      int n0 = __shfl(idx, j, 64);
      int n1 = __shfl(idx, j + 1, 64);
      float2 v0 = *(const float2*)(H + (size_t)n0 * HID + lane * 2);
      float2 v1 = *(const float2*)(H + (size_t)n1 * HID + lane * 2);
      a0.x += v0.x; a0.y += v0.y;
      a1.x += v1.x; a1.y += v1.y;
    }
    if (j < cnt) {
      int n0 = __shfl(idx, j, 64);
      float2 v0 = *(const float2*)(H + (size_t)n0 * HID + lane * 2);
      a0.x += v0.x; a0.y += v0.y;
    }
  }
  float inv = 1.f / (float)max(p1 - p0, 1);
  float2 o = make_float2((a0.x + a1.x) * inv, (a0.y + a1.y) * inv);
  *(float2*)(E + (size_t)gw * HID + lane * 2) = o;
}

// ---------------- node aggregation + scale + relu (writes h in place) --------
__global__ __launch_bounds__(256) void node_agg_kernel(
    const float* __restrict__ E, const int* __restrict__ nptr,
    const int* __restrict__ ncols, const float* __restrict__ scale,
    float* __restrict__ H)
{
  int gw = (blockIdx.x * blockDim.x + threadIdx.x) >> 6;
  int lane = threadIdx.x & 63;
  if (gw >= N_NODES) return;
  int p0 = nptr[gw] - NOFF, p1 = nptr[gw + 1] - NOFF;
  float2 a0 = make_float2(0.f, 0.f), a1 = make_float2(0.f, 0.f);
  for (int base = p0; base < p1; base += 64) {
    int cnt = min(64, p1 - base);
    int idx = (base + lane < p1) ? ncols[base + lane] : 0;
    int j = 0;
    for (; j + 1 < cnt; j += 2) {
      int e0 = __shfl(idx, j, 64);
      int e1 = __shfl(idx, j + 1, 64);
      float2 v0 = *(const float2*)(E + (size_t)e0 * HID + lane * 2);
      float2 v1 = *(const float2*)(E + (size_t)e1 * HID + lane * 2);
      a0.x += v0.x; a0.y += v0.y;
      a1.x += v1.x; a1.y += v1.y;
    }
    if (j < cnt) {
      int e0 = __shfl(idx, j, 64);
      float2 v0 = *(const float2*)(E + (size_t)e0 * HID + lane * 2);
      a0.x += v0.x; a0.y += v0.y;
    }
  }
  float inv = 1.f / (float)max(p1 - p0, 1);
  float2 sc = *(const float2*)(scale + lane * 2);
  float2 o;
  o.x = fmaxf((a0.x + a1.x) * inv * sc.x, 0.f);
  o.y = fmaxf((a0.y + a1.y) * inv * sc.y, 0.f);
  *(float2*)(H + (size_t)gw * HID + lane * 2) = o;
}

// ---------------- launch ----------------
extern "C" void kernel_launch(void* const* d_in, const int* in_sizes, int n_in,
                              void* d_out, int out_size, void* d_ws, size_t ws_size,
                              hipStream_t stream)
{
  const float* text = (const float*)d_in[0];
  const float* Wp   = (const float*)d_in[1];
  const float* bp   = (const float*)d_in[2];
  const float* W1a  = (const float*)d_in[3];
  const float* b1a  = (const float*)d_in[4];
  const float* W2a  = (const float*)d_in[5];
  const float* b2a  = (const float*)d_in[6];
  const float* W1b  = (const float*)d_in[7];
  const float* b1b  = (const float*)d_in[8];
  const float* W2b  = (const float*)d_in[9];
  const float* b2b  = (const float*)d_in[10];
  const int* node_idx = (const int*)d_in[11];
  const int* edge_idx = (const int*)d_in[12];
  float* H = (float*)d_out;

  // ---- workspace layout (bytes) ----
  char* ws = (char*)d_ws;
  int*   cnt   = (int*)(ws + 0);                         // 120000 ints (ecnt||ncnt)
  int*   ecnt  = cnt;
  int*   ncnt  = cnt + N_EDGES;
  int*   ecur  = (int*)(ws + 480000);                    // 20000
  int*   ncur  = (int*)(ws + 560000);                    // 100000
  float* gsum0 = (float*)(ws + 960000);                  // 128
  float* gsum1 = (float*)(ws + 960512);                  // 128
  const size_t zero_bytes = 961024;
  int*   cptr  = (int*)(ws + 961024);                    // 120001 ints (eptr||nptr+NOFF)
  int*   eptr  = cptr;
  int*   nptr  = cptr + N_EDGES;                         // values offset by +NOFF
  int*   ecols = (int*)(ws + 1441280);                   // 800000 ints
  int*   ncols = (int*)(ws + 4641280);                   // 800000 ints
  float* scale0 = (float*)(ws + 7841280);                // 128
  float* scale1 = (float*)(ws + 7841792);                // 128
  int*   partials = (int*)(ws + 7842304);                // 1024
  float* efeat = (float*)(ws + 7846400);                 // 20000*128 floats
  // Bh/Bl overlay the ecols region: only live from wprep until fill_kernel
  unsigned short* Bh = (unsigned short*)(ws + 1441280);  // 49152 shorts (96KB)
  unsigned short* Bl = (unsigned short*)(ws + 1539584);  // 49152 shorts

  hipMemsetAsync(ws, 0, zero_bytes, stream);

  // projection (MFMA bf16x3, LDS-staged B)
  wprep_kernel<<<96, 64, 0, stream>>>(Wp, Bh, Bl);
  proj_mfma<<<(N_NODES + 63) / 64, 256, 0, stream>>>(text, Bh, Bl, bp, H);

  // CSR build (merged edge+node scan over 120000 counters)
  count_kernel<<<N_INC / 256, 256, 0, stream>>>(node_idx, edge_idx, ecnt, ncnt);
  scan_block<<<118, 1024, 0, stream>>>(cnt, cptr, partials, 120000);
  scan_partials<<<1, 1024, 0, stream>>>(partials, 118, cptr, 120000);
  scan_add<<<118, 1024, 0, stream>>>(cptr, partials, 120000);
  fill_kernel<<<N_INC / 256, 256, 0, stream>>>(node_idx, edge_idx, eptr, ecur, ecols, nptr, ncur, ncols);

  // layer 1
  colsum_kernel<<<256, 256, 0, stream>>>(H, gsum0);
  scale_kernel<<<1, 128, 0, stream>>>(gsum0, W1a, b1a, W2a, b2a, scale0);
  edge_agg_kernel<<<(N_EDGES * 64) / 256, 256, 0, stream>>>(H, eptr, ecols, efeat);
  node_agg_kernel<<<(N_NODES * 64) / 256, 256, 0, stream>>>(efeat, nptr, ncols, scale0, H);

  // layer 2
  colsum_kernel<<<256, 256, 0, stream>>>(H, gsum1);
  scale_kernel<<<1, 128, 0, stream>>>(gsum1, W1b, b1b, W2b, b2b, scale1);
  edge_agg_kernel<<<(N_EDGES * 64) / 256, 256, 0, stream>>>(H, eptr, ecols, efeat);
  node_agg_kernel<<<(N_NODES * 64) / 256, 256, 0, stream>>>(efeat, nptr, ncols, scale1, H);
}